// Round 1
// baseline (23222.992 us; speedup 1.0000x reference)
//
#include <hip/hip_runtime.h>
#include <hip/hip_bf16.h>
#include <math.h>

// Problem dims (fixed by reference)
#define NL   24
#define DDIM 768
#define ED   1536
#define NST  16
#define KC   4
#define DTR  48
#define VV   1024
#define LL   512
#define BB   2
#define MM   (BB*LL)      // 1024
#define SP   80           // DT_RANK + 2N

__device__ __forceinline__ float softplusf(float x) {
    return fmaxf(x, 0.0f) + log1pf(expf(-fabsf(x)));
}
__device__ __forceinline__ float siluf(float x) {
    return x / (1.0f + expf(-x));
}

// ---------------- embedding: h[m,:] = embed[src[l,b],:], m = b*L + l -------
__global__ __launch_bounds__(256) void embed_kernel(
        const int* __restrict__ src, const float* __restrict__ emb,
        float* __restrict__ h)
{
    int m = blockIdx.x;
    int b = m >> 9;           // m / L
    int l = m & (LL - 1);
    int v = src[l * BB + b];
    const float* er = emb + (size_t)v * DDIM;
    float* hr = h + (size_t)m * DDIM;
    for (int d = threadIdx.x; d < DDIM; d += 256) hr[d] = er[d];
}

// ---------------- rmsnorm: o[m,:] = x[m,:] * rsqrt(mean(x^2)+eps) * w ------
__global__ __launch_bounds__(256) void rmsnorm_kernel(
        const float* __restrict__ x, const float* __restrict__ w,
        float* __restrict__ o)
{
    __shared__ float red[4];
    int m = blockIdx.x, tid = threadIdx.x;
    const float* xr = x + (size_t)m * DDIM;
    float v0 = xr[tid], v1 = xr[tid + 256], v2 = xr[tid + 512];
    float s = v0 * v0 + v1 * v1 + v2 * v2;
    #pragma unroll
    for (int off = 32; off; off >>= 1) s += __shfl_down(s, off);
    if ((tid & 63) == 0) red[tid >> 6] = s;
    __syncthreads();
    float tot = red[0] + red[1] + red[2] + red[3];
    float scale = rsqrtf(tot * (1.0f / DDIM) + 1e-5f);
    float* orow = o + (size_t)m * DDIM;
    orow[tid]       = v0 * scale * w[tid];
    orow[tid + 256] = v1 * scale * w[tid + 256];
    orow[tid + 512] = v2 * scale * w[tid + 512];
}

// ---------------- generic SGEMM: C[m,n] = sum_k A[m,k]*W[n,k] --------------
// modes: 0 = store; 1 = softplus(acc + bias[n]); 2 = C += acc (residual);
//        3 = logits store with [B,L]->[L,B] transpose (ldc = V)
__global__ __launch_bounds__(256) void sgemm_nt(
        const float* __restrict__ A, int lda,
        const float* __restrict__ W, int ldb,
        float* __restrict__ C, int ldc,
        int Nmat, int Kdim, int mode, const float* __restrict__ bias)
{
    __shared__ float As[16][65];
    __shared__ float Ws[16][65];
    int tid = threadIdx.x;
    int tx = tid & 15, ty = tid >> 4;
    int rowBase = blockIdx.x * 64;
    int colBase = blockIdx.y * 64;
    float acc[4][4] = {};

    for (int kk = 0; kk < Kdim; kk += 16) {
        #pragma unroll
        for (int i = 0; i < 4; i++) {
            int idx = tid + i * 256;
            int r = idx >> 4, kc = idx & 15;
            As[kc][r] = A[(size_t)(rowBase + r) * lda + kk + kc];
            int cG = colBase + r;
            Ws[kc][r] = (cG < Nmat) ? W[(size_t)cG * ldb + kk + kc] : 0.0f;
        }
        __syncthreads();
        #pragma unroll
        for (int k = 0; k < 16; k++) {
            float av[4], bv[4];
            #pragma unroll
            for (int i = 0; i < 4; i++) av[i] = As[k][ty + 16 * i];
            #pragma unroll
            for (int j = 0; j < 4; j++) bv[j] = Ws[k][tx + 16 * j];
            #pragma unroll
            for (int i = 0; i < 4; i++)
                #pragma unroll
                for (int j = 0; j < 4; j++)
                    acc[i][j] = fmaf(av[i], bv[j], acc[i][j]);
        }
        __syncthreads();
    }

    #pragma unroll
    for (int i = 0; i < 4; i++) {
        int m = rowBase + ty + 16 * i;
        #pragma unroll
        for (int j = 0; j < 4; j++) {
            int n = colBase + tx + 16 * j;
            if (n >= Nmat) continue;
            float v = acc[i][j];
            if (mode == 0) {
                C[(size_t)m * ldc + n] = v;
            } else if (mode == 1) {
                C[(size_t)m * ldc + n] = softplusf(v + bias[n]);
            } else if (mode == 2) {
                C[(size_t)m * ldc + n] += v;
            } else {
                int l = m & (LL - 1), b = m >> 9;
                C[((size_t)l * BB + b) * ldc + n] = v;
            }
        }
    }
}

// ---------------- depthwise causal conv (K=4) + bias + SiLU ----------------
// u = ug[:, 0:ED] (ug row stride 2*ED); uc[m,e] = silu(sum_k u[b,l+k-3,e]*cw[e,k]+cb[e])
__global__ __launch_bounds__(256) void conv_silu_kernel(
        const float* __restrict__ ug, const float* __restrict__ cw,
        const float* __restrict__ cb, float* __restrict__ uc)
{
    int e = blockIdx.x * 256 + threadIdx.x;
    int m = blockIdx.y;
    int b = m >> 9, l = m & (LL - 1);
    float acc = cb[e];
    #pragma unroll
    for (int k = 0; k < KC; k++) {
        int ll = l + k - (KC - 1);
        float uv = (ll >= 0) ? ug[((size_t)(b * LL + ll)) * (2 * ED) + e] : 0.0f;
        acc = fmaf(uv, cw[e * KC + k], acc);
    }
    uc[(size_t)m * ED + e] = siluf(acc);
}

// ---------------- selective scan, thread per (b, e, n) ---------------------
// block: 256 = 16 e x 16 n; grid: B * ED/16 = 192
__global__ __launch_bounds__(256) void scan_kernel(
        const float* __restrict__ dtb, const float* __restrict__ ucb,
        const float* __restrict__ spb, const float* __restrict__ ugb,
        const float* __restrict__ A_log, const float* __restrict__ Dp,
        float* __restrict__ yb)
{
    int tid = threadIdx.x;
    int n = tid & 15;
    int eloc = tid >> 4;
    const int blocksPerB = ED / 16;   // 96
    int b = blockIdx.x / blocksPerB;
    int e = (blockIdx.x % blocksPerB) * 16 + eloc;
    float a = -expf(A_log[(size_t)e * NST + n]);
    float dpv = Dp[e];
    float hst = 0.0f;
    for (int l = 0; l < LL; ++l) {
        int m = b * LL + l;
        float dtv = dtb[(size_t)m * ED + e];
        float ucv = ucb[(size_t)m * ED + e];
        float bvn = spb[(size_t)m * SP + DTR + n];
        float cvn = spb[(size_t)m * SP + DTR + NST + n];
        float dA = expf(dtv * a);
        hst = fmaf(dA, hst, (dtv * ucv) * bvn);
        float yp = hst * cvn;
        yp += __shfl_xor(yp, 1);
        yp += __shfl_xor(yp, 2);
        yp += __shfl_xor(yp, 4);
        yp += __shfl_xor(yp, 8);
        if (n == 0) {
            float g = ugb[(size_t)m * (2 * ED) + ED + e];
            float yv = yp + ucv * dpv;
            yb[(size_t)m * ED + e] = yv * siluf(g);
        }
    }
}

extern "C" void kernel_launch(void* const* d_in, const int* in_sizes, int n_in,
                              void* d_out, int out_size, void* d_ws, size_t ws_size,
                              hipStream_t stream) {
    const int*   src    = (const int*)  d_in[0];
    const float* emb    = (const float*)d_in[1];
    const float* norm_w = (const float*)d_in[2];
    const float* in_prj = (const float*)d_in[3];
    const float* conv_w = (const float*)d_in[4];
    const float* conv_b = (const float*)d_in[5];
    const float* x_prj  = (const float*)d_in[6];
    const float* dt_w   = (const float*)d_in[7];
    const float* dt_b   = (const float*)d_in[8];
    const float* A_log  = (const float*)d_in[9];
    const float* Dp     = (const float*)d_in[10];
    const float* out_p  = (const float*)d_in[11];
    const float* normf  = (const float*)d_in[12];
    float* out = (float*)d_out;

    float* ws   = (float*)d_ws;
    float* h    = ws;                            // M*D
    float* xn   = h    + (size_t)MM * DDIM;      // M*D
    float* ug   = xn   + (size_t)MM * DDIM;      // M*2ED
    float* ucb  = ug   + (size_t)MM * 2 * ED;    // M*ED
    float* spb  = ucb  + (size_t)MM * ED;        // M*SP
    float* dtbf = spb  + (size_t)MM * SP;        // M*ED
    float* yb   = dtbf + (size_t)MM * ED;        // M*ED

    embed_kernel<<<MM, 256, 0, stream>>>(src, emb, h);

    for (int layer = 0; layer < NL; layer++) {
        rmsnorm_kernel<<<MM, 256, 0, stream>>>(h, norm_w + (size_t)layer * DDIM, xn);
        // ug = xn @ in_proj^T   [M, 2ED]
        sgemm_nt<<<dim3(MM / 64, 2 * ED / 64), 256, 0, stream>>>(
            xn, DDIM, in_prj + (size_t)layer * 2 * ED * DDIM, DDIM,
            ug, 2 * ED, 2 * ED, DDIM, 0, nullptr);
        conv_silu_kernel<<<dim3(ED / 256, MM), 256, 0, stream>>>(
            ug, conv_w + (size_t)layer * ED * KC, conv_b + (size_t)layer * ED, ucb);
        // sp = uc @ x_proj^T    [M, 80]
        sgemm_nt<<<dim3(MM / 64, 2), 256, 0, stream>>>(
            ucb, ED, x_prj + (size_t)layer * SP * ED, ED,
            spb, SP, SP, ED, 0, nullptr);
        // dt = softplus(sp[:, :48] @ dt_w^T + dt_b)   [M, ED]
        sgemm_nt<<<dim3(MM / 64, ED / 64), 256, 0, stream>>>(
            spb, SP, dt_w + (size_t)layer * ED * DTR, DTR,
            dtbf, ED, ED, DTR, 1, dt_b + (size_t)layer * ED);
        scan_kernel<<<BB * ED / 16, 256, 0, stream>>>(
            dtbf, ucb, spb, ug,
            A_log + (size_t)layer * ED * NST, Dp + (size_t)layer * ED, yb);
        // h += y @ out_proj^T   [M, D]
        sgemm_nt<<<dim3(MM / 64, DDIM / 64), 256, 0, stream>>>(
            yb, ED, out_p + (size_t)layer * DDIM * ED, ED,
            h, DDIM, DDIM, ED, 2, nullptr);
    }

    rmsnorm_kernel<<<MM, 256, 0, stream>>>(h, normf, xn);
    // logits = xn @ embed^T, stored transposed to [L, B, V]
    sgemm_nt<<<dim3(MM / 64, VV / 64), 256, 0, stream>>>(
        xn, DDIM, emb, DDIM, out, VV, VV, DDIM, 3, nullptr);
}

// Round 2
// 14712.425 us; speedup vs baseline: 1.5785x; 1.5785x over previous
//
#include <hip/hip_runtime.h>
#include <hip/hip_bf16.h>
#include <math.h>

// Problem dims (fixed by reference)
#define NL   24
#define DDIM 768
#define ED   1536
#define NST  16
#define KC   4
#define DTR  48
#define VV   1024
#define LL   512
#define BB   2
#define MM   (BB*LL)      // 1024
#define SP   80           // DT_RANK + 2N

// scan chunking
#define NC   32           // chunks per sequence
#define CL   (LL/NC)      // 16 timesteps per chunk

__device__ __forceinline__ float softplusf(float x) {
    return fmaxf(x, 0.0f) + log1pf(expf(-fabsf(x)));
}
__device__ __forceinline__ float siluf(float x) {
    return x / (1.0f + expf(-x));
}

// ---------------- embedding: h[m,:] = embed[src[l,b],:], m = b*L + l -------
__global__ __launch_bounds__(256) void embed_kernel(
        const int* __restrict__ src, const float* __restrict__ emb,
        float* __restrict__ h)
{
    int m = blockIdx.x;
    int b = m >> 9;           // m / L
    int l = m & (LL - 1);
    int v = src[l * BB + b];
    const float* er = emb + (size_t)v * DDIM;
    float* hr = h + (size_t)m * DDIM;
    for (int d = threadIdx.x; d < DDIM; d += 256) hr[d] = er[d];
}

// ---------------- rmsnorm: o[m,:] = x[m,:] * rsqrt(mean(x^2)+eps) * w ------
__global__ __launch_bounds__(256) void rmsnorm_kernel(
        const float* __restrict__ x, const float* __restrict__ w,
        float* __restrict__ o)
{
    __shared__ float red[4];
    int m = blockIdx.x, tid = threadIdx.x;
    const float* xr = x + (size_t)m * DDIM;
    float v0 = xr[tid], v1 = xr[tid + 256], v2 = xr[tid + 512];
    float s = v0 * v0 + v1 * v1 + v2 * v2;
    #pragma unroll
    for (int off = 32; off; off >>= 1) s += __shfl_down(s, off);
    if ((tid & 63) == 0) red[tid >> 6] = s;
    __syncthreads();
    float tot = red[0] + red[1] + red[2] + red[3];
    float scale = rsqrtf(tot * (1.0f / DDIM) + 1e-5f);
    float* orow = o + (size_t)m * DDIM;
    orow[tid]       = v0 * scale * w[tid];
    orow[tid + 256] = v1 * scale * w[tid + 256];
    orow[tid + 512] = v2 * scale * w[tid + 512];
}

// ---------------- generic SGEMM: C[m,n] = sum_k A[m,k]*W[n,k] --------------
// modes: 0 = store; 1 = softplus(acc + bias[n]); 2 = C += acc (residual);
//        3 = logits store with [B,L]->[L,B] transpose (ldc = V)
__global__ __launch_bounds__(256) void sgemm_nt(
        const float* __restrict__ A, int lda,
        const float* __restrict__ W, int ldb,
        float* __restrict__ C, int ldc,
        int Nmat, int Kdim, int mode, const float* __restrict__ bias)
{
    __shared__ float As[16][65];
    __shared__ float Ws[16][65];
    int tid = threadIdx.x;
    int tx = tid & 15, ty = tid >> 4;
    int rowBase = blockIdx.x * 64;
    int colBase = blockIdx.y * 64;
    float acc[4][4] = {};

    for (int kk = 0; kk < Kdim; kk += 16) {
        #pragma unroll
        for (int i = 0; i < 4; i++) {
            int idx = tid + i * 256;
            int r = idx >> 4, kc = idx & 15;
            As[kc][r] = A[(size_t)(rowBase + r) * lda + kk + kc];
            int cG = colBase + r;
            Ws[kc][r] = (cG < Nmat) ? W[(size_t)cG * ldb + kk + kc] : 0.0f;
        }
        __syncthreads();
        #pragma unroll
        for (int k = 0; k < 16; k++) {
            float av[4], bv[4];
            #pragma unroll
            for (int i = 0; i < 4; i++) av[i] = As[k][ty + 16 * i];
            #pragma unroll
            for (int j = 0; j < 4; j++) bv[j] = Ws[k][tx + 16 * j];
            #pragma unroll
            for (int i = 0; i < 4; i++)
                #pragma unroll
                for (int j = 0; j < 4; j++)
                    acc[i][j] = fmaf(av[i], bv[j], acc[i][j]);
        }
        __syncthreads();
    }

    #pragma unroll
    for (int i = 0; i < 4; i++) {
        int m = rowBase + ty + 16 * i;
        #pragma unroll
        for (int j = 0; j < 4; j++) {
            int n = colBase + tx + 16 * j;
            if (n >= Nmat) continue;
            float v = acc[i][j];
            if (mode == 0) {
                C[(size_t)m * ldc + n] = v;
            } else if (mode == 1) {
                C[(size_t)m * ldc + n] = softplusf(v + bias[n]);
            } else if (mode == 2) {
                C[(size_t)m * ldc + n] += v;
            } else {
                int l = m & (LL - 1), b = m >> 9;
                C[((size_t)l * BB + b) * ldc + n] = v;
            }
        }
    }
}

// ---------------- depthwise causal conv (K=4) + bias + SiLU ----------------
__global__ __launch_bounds__(256) void conv_silu_kernel(
        const float* __restrict__ ug, const float* __restrict__ cw,
        const float* __restrict__ cb, float* __restrict__ uc)
{
    int e = blockIdx.x * 256 + threadIdx.x;
    int m = blockIdx.y;
    int b = m >> 9, l = m & (LL - 1);
    float acc = cb[e];
    #pragma unroll
    for (int k = 0; k < KC; k++) {
        int ll = l + k - (KC - 1);
        float uv = (ll >= 0) ? ug[((size_t)(b * LL + ll)) * (2 * ED) + e] : 0.0f;
        acc = fmaf(uv, cw[e * KC + k], acc);
    }
    uc[(size_t)m * ED + e] = siluf(acc);
}

// ================= chunked selective scan ==================================
// thread = one (b, e, chunk); N=16 states in registers.
// pass1: h_init = 0, emit chunk-final h[16] and sum(dt) over chunk.
// mid:   serial combine over chunks -> h_start per chunk.
// pass2: h_init = h_start, full y epilogue.

// pass1: grid (ED/256, NC, B), block 256 (one e per thread)
__global__ __launch_bounds__(256) void scan_pass1(
        const float* __restrict__ dtb, const float* __restrict__ ucb,
        const float* __restrict__ spb, const float* __restrict__ A_log,
        float* __restrict__ hfin, float* __restrict__ sumdt)
{
    int e = blockIdx.x * 256 + threadIdx.x;
    int c = blockIdx.y;
    int b = blockIdx.z;
    float a[NST], h[NST];
    const float4* ap = reinterpret_cast<const float4*>(A_log + (size_t)e * NST);
    #pragma unroll
    for (int q = 0; q < 4; q++) {
        float4 v = ap[q];
        a[4*q+0] = -expf(v.x); a[4*q+1] = -expf(v.y);
        a[4*q+2] = -expf(v.z); a[4*q+3] = -expf(v.w);
    }
    #pragma unroll
    for (int n = 0; n < NST; n++) h[n] = 0.0f;
    float sdt = 0.0f;
    int m0 = b * LL + c * CL;
    for (int l = 0; l < CL; l++) {
        int m = m0 + l;
        float dtv = dtb[(size_t)m * ED + e];
        float ucv = ucb[(size_t)m * ED + e];
        const float4* bp = reinterpret_cast<const float4*>(spb + (size_t)m * SP + DTR);
        float x = dtv * ucv;
        sdt += dtv;
        #pragma unroll
        for (int q = 0; q < 4; q++) {
            float4 bv = bp[q];
            h[4*q+0] = fmaf(expf(dtv * a[4*q+0]), h[4*q+0], x * bv.x);
            h[4*q+1] = fmaf(expf(dtv * a[4*q+1]), h[4*q+1], x * bv.y);
            h[4*q+2] = fmaf(expf(dtv * a[4*q+2]), h[4*q+2], x * bv.z);
            h[4*q+3] = fmaf(expf(dtv * a[4*q+3]), h[4*q+3], x * bv.w);
        }
    }
    float* hf = hfin + (((size_t)(b * ED + e)) * NC + c) * NST;
    #pragma unroll
    for (int n = 0; n < NST; n++) hf[n] = h[n];
    sumdt[((size_t)(b * ED + e)) * NC + c] = sdt;
}

// mid: thread per (b,e,n); grid B*ED*NST/256
__global__ __launch_bounds__(256) void scan_mid(
        const float* __restrict__ hfin, const float* __restrict__ sumdt,
        const float* __restrict__ A_log, float* __restrict__ hstart)
{
    int gid = blockIdx.x * 256 + threadIdx.x;   // (b*ED+e)*16 + n
    int n = gid & 15;
    int be = gid >> 4;
    int e = be % ED;
    float a = -expf(A_log[(size_t)e * NST + n]);
    float h = 0.0f;
    const float* hf = hfin + (size_t)be * NC * NST;
    const float* sd = sumdt + (size_t)be * NC;
    float* hs = hstart + (size_t)be * NC * NST;
    for (int c = 0; c < NC; c++) {
        hs[c * NST + n] = h;
        h = fmaf(expf(a * sd[c]), h, hf[c * NST + n]);
    }
}

// pass2: grid (ED/256, NC, B), block 256
__global__ __launch_bounds__(256) void scan_pass2(
        const float* __restrict__ dtb, const float* __restrict__ ucb,
        const float* __restrict__ spb, const float* __restrict__ ugb,
        const float* __restrict__ A_log, const float* __restrict__ Dp,
        const float* __restrict__ hstart, float* __restrict__ yb)
{
    int e = blockIdx.x * 256 + threadIdx.x;
    int c = blockIdx.y;
    int b = blockIdx.z;
    float a[NST], h[NST];
    const float4* ap = reinterpret_cast<const float4*>(A_log + (size_t)e * NST);
    #pragma unroll
    for (int q = 0; q < 4; q++) {
        float4 v = ap[q];
        a[4*q+0] = -expf(v.x); a[4*q+1] = -expf(v.y);
        a[4*q+2] = -expf(v.z); a[4*q+3] = -expf(v.w);
    }
    const float* hs = hstart + (((size_t)(b * ED + e)) * NC + c) * NST;
    #pragma unroll
    for (int n = 0; n < NST; n++) h[n] = hs[n];
    float dpv = Dp[e];
    int m0 = b * LL + c * CL;
    for (int l = 0; l < CL; l++) {
        int m = m0 + l;
        float dtv = dtb[(size_t)m * ED + e];
        float ucv = ucb[(size_t)m * ED + e];
        const float4* bp = reinterpret_cast<const float4*>(spb + (size_t)m * SP + DTR);
        const float4* cp = reinterpret_cast<const float4*>(spb + (size_t)m * SP + DTR + NST);
        float g = ugb[(size_t)m * (2 * ED) + ED + e];
        float x = dtv * ucv;
        float y0 = 0.0f, y1 = 0.0f, y2 = 0.0f, y3 = 0.0f;
        #pragma unroll
        for (int q = 0; q < 4; q++) {
            float4 bv = bp[q];
            float4 cv = cp[q];
            h[4*q+0] = fmaf(expf(dtv * a[4*q+0]), h[4*q+0], x * bv.x);
            h[4*q+1] = fmaf(expf(dtv * a[4*q+1]), h[4*q+1], x * bv.y);
            h[4*q+2] = fmaf(expf(dtv * a[4*q+2]), h[4*q+2], x * bv.z);
            h[4*q+3] = fmaf(expf(dtv * a[4*q+3]), h[4*q+3], x * bv.w);
            y0 = fmaf(h[4*q+0], cv.x, y0);
            y1 = fmaf(h[4*q+1], cv.y, y1);
            y2 = fmaf(h[4*q+2], cv.z, y2);
            y3 = fmaf(h[4*q+3], cv.w, y3);
        }
        float yv = (y0 + y1) + (y2 + y3) + ucv * dpv;
        yb[(size_t)m * ED + e] = yv * siluf(g);
    }
}

extern "C" void kernel_launch(void* const* d_in, const int* in_sizes, int n_in,
                              void* d_out, int out_size, void* d_ws, size_t ws_size,
                              hipStream_t stream) {
    const int*   src    = (const int*)  d_in[0];
    const float* emb    = (const float*)d_in[1];
    const float* norm_w = (const float*)d_in[2];
    const float* in_prj = (const float*)d_in[3];
    const float* conv_w = (const float*)d_in[4];
    const float* conv_b = (const float*)d_in[5];
    const float* x_prj  = (const float*)d_in[6];
    const float* dt_w   = (const float*)d_in[7];
    const float* dt_b   = (const float*)d_in[8];
    const float* A_log  = (const float*)d_in[9];
    const float* Dp     = (const float*)d_in[10];
    const float* out_p  = (const float*)d_in[11];
    const float* normf  = (const float*)d_in[12];
    float* out = (float*)d_out;

    float* ws    = (float*)d_ws;
    float* h     = ws;                              // M*D
    float* xn    = h     + (size_t)MM * DDIM;       // M*D
    float* ug    = xn    + (size_t)MM * DDIM;       // M*2ED
    float* ucb   = ug    + (size_t)MM * 2 * ED;     // M*ED
    float* spb   = ucb   + (size_t)MM * ED;         // M*SP
    float* dtbf  = spb   + (size_t)MM * SP;         // M*ED
    float* yb    = dtbf  + (size_t)MM * ED;         // M*ED
    float* hfin  = yb    + (size_t)MM * ED;         // B*ED*NC*NST
    float* sumdt = hfin  + (size_t)BB * ED * NC * NST; // B*ED*NC
    float* hstart= sumdt + (size_t)BB * ED * NC;    // B*ED*NC*NST

    embed_kernel<<<MM, 256, 0, stream>>>(src, emb, h);

    for (int layer = 0; layer < NL; layer++) {
        rmsnorm_kernel<<<MM, 256, 0, stream>>>(h, norm_w + (size_t)layer * DDIM, xn);
        // ug = xn @ in_proj^T   [M, 2ED]
        sgemm_nt<<<dim3(MM / 64, 2 * ED / 64), 256, 0, stream>>>(
            xn, DDIM, in_prj + (size_t)layer * 2 * ED * DDIM, DDIM,
            ug, 2 * ED, 2 * ED, DDIM, 0, nullptr);
        conv_silu_kernel<<<dim3(ED / 256, MM), 256, 0, stream>>>(
            ug, conv_w + (size_t)layer * ED * KC, conv_b + (size_t)layer * ED, ucb);
        // sp = uc @ x_proj^T    [M, 80]
        sgemm_nt<<<dim3(MM / 64, 2), 256, 0, stream>>>(
            ucb, ED, x_prj + (size_t)layer * SP * ED, ED,
            spb, SP, SP, ED, 0, nullptr);
        // dt = softplus(sp[:, :48] @ dt_w^T + dt_b)   [M, ED]
        sgemm_nt<<<dim3(MM / 64, ED / 64), 256, 0, stream>>>(
            spb, SP, dt_w + (size_t)layer * ED * DTR, DTR,
            dtbf, ED, ED, DTR, 1, dt_b + (size_t)layer * ED);
        // chunked scan
        scan_pass1<<<dim3(ED / 256, NC, BB), 256, 0, stream>>>(
            dtbf, ucb, spb, A_log + (size_t)layer * ED * NST, hfin, sumdt);
        scan_mid<<<BB * ED * NST / 256, 256, 0, stream>>>(
            hfin, sumdt, A_log + (size_t)layer * ED * NST, hstart);
        scan_pass2<<<dim3(ED / 256, NC, BB), 256, 0, stream>>>(
            dtbf, ucb, spb, ug, A_log + (size_t)layer * ED * NST,
            Dp + (size_t)layer * ED, hstart, yb);
        // h += y @ out_proj^T   [M, D]
        sgemm_nt<<<dim3(MM / 64, DDIM / 64), 256, 0, stream>>>(
            yb, ED, out_p + (size_t)layer * DDIM * ED, ED,
            h, DDIM, DDIM, ED, 2, nullptr);
    }

    rmsnorm_kernel<<<MM, 256, 0, stream>>>(h, normf, xn);
    // logits = xn @ embed^T, stored transposed to [L, B, V]
    sgemm_nt<<<dim3(MM / 64, VV / 64), 256, 0, stream>>>(
        xn, DDIM, emb, DDIM, out, VV, VV, DDIM, 3, nullptr);
}

// Round 3
// 9772.559 us; speedup vs baseline: 2.3763x; 1.5055x over previous
//
#include <hip/hip_runtime.h>
#include <hip/hip_bf16.h>
#include <math.h>

// Problem dims (fixed by reference)
#define NL   24
#define DDIM 768
#define ED   1536
#define NST  16
#define KC   4
#define DTR  48
#define VV   1024
#define LL   512
#define BB   2
#define MM   (BB*LL)      // 1024
#define SP   80           // DT_RANK + 2N

// scan chunking
#define NC   32           // chunks per sequence
#define CL   (LL/NC)      // 16 timesteps per chunk

typedef __bf16 bf16x8 __attribute__((ext_vector_type(8)));
typedef float  floatx4 __attribute__((ext_vector_type(4)));
typedef unsigned short ushort8 __attribute__((ext_vector_type(8)));

__device__ __forceinline__ float softplusf(float x) {
    return fmaxf(x, 0.0f) + log1pf(expf(-fabsf(x)));
}
__device__ __forceinline__ float siluf(float x) {
    return x / (1.0f + expf(-x));
}
__device__ __forceinline__ unsigned short f2bf(float x) {
    unsigned int u = __builtin_bit_cast(unsigned int, x);
    u += 0x7FFFu + ((u >> 16) & 1u);   // round-to-nearest-even
    return (unsigned short)(u >> 16);
}

// ---------------- embedding: h[m,:] = embed[src[l,b],:], m = b*L + l -------
__global__ __launch_bounds__(256) void embed_kernel(
        const int* __restrict__ src, const float* __restrict__ emb,
        float* __restrict__ h)
{
    int m = blockIdx.x;
    int b = m >> 9;           // m / L
    int l = m & (LL - 1);
    int v = src[l * BB + b];
    const float* er = emb + (size_t)v * DDIM;
    float* hr = h + (size_t)m * DDIM;
    for (int d = threadIdx.x; d < DDIM; d += 256) hr[d] = er[d];
}

// ---------------- rmsnorm: o[m,:] = x[m,:] * rsqrt(mean(x^2)+eps) * w ------
__global__ __launch_bounds__(256) void rmsnorm_kernel(
        const float* __restrict__ x, const float* __restrict__ w,
        float* __restrict__ o)
{
    __shared__ float red[4];
    int m = blockIdx.x, tid = threadIdx.x;
    const float* xr = x + (size_t)m * DDIM;
    float v0 = xr[tid], v1 = xr[tid + 256], v2 = xr[tid + 512];
    float s = v0 * v0 + v1 * v1 + v2 * v2;
    #pragma unroll
    for (int off = 32; off; off >>= 1) s += __shfl_down(s, off);
    if ((tid & 63) == 0) red[tid >> 6] = s;
    __syncthreads();
    float tot = red[0] + red[1] + red[2] + red[3];
    float scale = rsqrtf(tot * (1.0f / DDIM) + 1e-5f);
    float* orow = o + (size_t)m * DDIM;
    orow[tid]       = v0 * scale * w[tid];
    orow[tid + 256] = v1 * scale * w[tid + 256];
    orow[tid + 512] = v2 * scale * w[tid + 512];
}

// ============ bf16 MFMA GEMM: C[m,n] = sum_k A[m,k]*W[n,k] =================
// A fp32 [M,lda] row-major, W fp32 [N,ldb] row-major (both K-contiguous).
// fp32 tiles are converted to bf16 while staging into LDS.
// BM=BN=128, BK=32; 256 threads = 4 waves in 2x2; wave does 4x4 16x16 MFMAs.
// LDS chunk = 8 bf16 (16B). chunk (row r, col-chunk c) lives at slot
// r*4 + (c ^ ((r>>1)&3))  -> fragment ds_read_b128 is 2-way max on banks.
// modes: 0 = store; 2 = C += acc; 3 = logits store with [B,L]->[L,B] transpose
__global__ __launch_bounds__(256) void gemm_bf16nt(
        const float* __restrict__ A, int lda,
        const float* __restrict__ W, int ldb,
        float* __restrict__ C, int ldc,
        int Kdim, int mode)
{
    __shared__ unsigned short As[128 * 32];
    __shared__ unsigned short Bs[128 * 32];
    int tid  = threadIdx.x;
    int lane = tid & 63;
    int wave = tid >> 6;
    int wm = wave >> 1, wn = wave & 1;
    int rowBase = blockIdx.x * 128;
    int colBase = blockIdx.y * 128;

    floatx4 acc[4][4];
    #pragma unroll
    for (int i = 0; i < 4; i++)
        #pragma unroll
        for (int j = 0; j < 4; j++)
            acc[i][j] = (floatx4){0.f, 0.f, 0.f, 0.f};

    int kc  = lane >> 4;      // k-chunk 0..3 for fragment reads
    int lm  = lane & 15;

    for (int kk = 0; kk < Kdim; kk += 32) {
        // ---- stage 128x32 fp32 -> bf16 LDS, for A and W ----
        #pragma unroll
        for (int hh = 0; hh < 2; hh++) {
            int q  = tid + hh * 256;          // chunk id 0..511
            int r  = q >> 2;                  // tile row 0..127
            int cg = q & 3;                   // global col-chunk
            int cs = cg ^ ((r >> 1) & 3);     // swizzled LDS slot
            const float4* pa = reinterpret_cast<const float4*>(
                A + (size_t)(rowBase + r) * lda + kk + cg * 8);
            float4 a0 = pa[0], a1 = pa[1];
            const float4* pb = reinterpret_cast<const float4*>(
                W + (size_t)(colBase + r) * ldb + kk + cg * 8);
            float4 b0 = pb[0], b1 = pb[1];
            ushort8 va = {f2bf(a0.x), f2bf(a0.y), f2bf(a0.z), f2bf(a0.w),
                          f2bf(a1.x), f2bf(a1.y), f2bf(a1.z), f2bf(a1.w)};
            ushort8 vb = {f2bf(b0.x), f2bf(b0.y), f2bf(b0.z), f2bf(b0.w),
                          f2bf(b1.x), f2bf(b1.y), f2bf(b1.z), f2bf(b1.w)};
            *reinterpret_cast<ushort8*>(&As[(r * 4 + cs) * 8]) = va;
            *reinterpret_cast<ushort8*>(&Bs[(r * 4 + cs) * 8]) = vb;
        }
        __syncthreads();

        // ---- fragments: A[m = lane&15][k = (lane>>4)*8 + j] ----
        bf16x8 af[4], bff[4];
        #pragma unroll
        for (int i = 0; i < 4; i++) {
            int m = wm * 64 + i * 16 + lm;
            af[i]  = *reinterpret_cast<bf16x8*>(&As[(m * 4 + (kc ^ ((m >> 1) & 3))) * 8]);
            int n = wn * 64 + i * 16 + lm;
            bff[i] = *reinterpret_cast<bf16x8*>(&Bs[(n * 4 + (kc ^ ((n >> 1) & 3))) * 8]);
        }
        #pragma unroll
        for (int i = 0; i < 4; i++)
            #pragma unroll
            for (int j = 0; j < 4; j++)
                acc[i][j] = __builtin_amdgcn_mfma_f32_16x16x32_bf16(
                    af[i], bff[j], acc[i][j], 0, 0, 0);
        __syncthreads();
    }

    // ---- epilogue: D col = lane&15, row = (lane>>4)*4 + reg ----
    int c4 = (lane >> 4) * 4;
    #pragma unroll
    for (int i = 0; i < 4; i++) {
        #pragma unroll
        for (int j = 0; j < 4; j++) {
            floatx4 v = acc[i][j];
            int col = colBase + wn * 64 + j * 16 + lm;
            #pragma unroll
            for (int p = 0; p < 4; p++) {
                int row = rowBase + wm * 64 + i * 16 + c4 + p;
                if (mode == 0) {
                    C[(size_t)row * ldc + col] = v[p];
                } else if (mode == 2) {
                    C[(size_t)row * ldc + col] += v[p];
                } else {
                    int l = row & (LL - 1), b = row >> 9;
                    C[((size_t)l * BB + b) * ldc + col] = v[p];
                }
            }
        }
    }
}

// ---------------- generic fp32 SGEMM (small GEMMs: x_proj, dt) -------------
// modes: 0 = store; 1 = softplus(acc + bias[n])
__global__ __launch_bounds__(256) void sgemm_nt(
        const float* __restrict__ A, int lda,
        const float* __restrict__ W, int ldb,
        float* __restrict__ C, int ldc,
        int Nmat, int Kdim, int mode, const float* __restrict__ bias)
{
    __shared__ float As[16][65];
    __shared__ float Ws[16][65];
    int tid = threadIdx.x;
    int tx = tid & 15, ty = tid >> 4;
    int rowBase = blockIdx.x * 64;
    int colBase = blockIdx.y * 64;
    float acc[4][4] = {};

    for (int kk = 0; kk < Kdim; kk += 16) {
        #pragma unroll
        for (int i = 0; i < 4; i++) {
            int idx = tid + i * 256;
            int r = idx >> 4, kc = idx & 15;
            As[kc][r] = A[(size_t)(rowBase + r) * lda + kk + kc];
            int cG = colBase + r;
            Ws[kc][r] = (cG < Nmat) ? W[(size_t)cG * ldb + kk + kc] : 0.0f;
        }
        __syncthreads();
        #pragma unroll
        for (int k = 0; k < 16; k++) {
            float av[4], bv[4];
            #pragma unroll
            for (int i = 0; i < 4; i++) av[i] = As[k][ty + 16 * i];
            #pragma unroll
            for (int j = 0; j < 4; j++) bv[j] = Ws[k][tx + 16 * j];
            #pragma unroll
            for (int i = 0; i < 4; i++)
                #pragma unroll
                for (int j = 0; j < 4; j++)
                    acc[i][j] = fmaf(av[i], bv[j], acc[i][j]);
        }
        __syncthreads();
    }

    #pragma unroll
    for (int i = 0; i < 4; i++) {
        int m = rowBase + ty + 16 * i;
        #pragma unroll
        for (int j = 0; j < 4; j++) {
            int n = colBase + tx + 16 * j;
            if (n >= Nmat) continue;
            float v = acc[i][j];
            if (mode == 0) {
                C[(size_t)m * ldc + n] = v;
            } else {
                C[(size_t)m * ldc + n] = softplusf(v + bias[n]);
            }
        }
    }
}

// ---------------- depthwise causal conv (K=4) + bias + SiLU ----------------
__global__ __launch_bounds__(256) void conv_silu_kernel(
        const float* __restrict__ ug, const float* __restrict__ cw,
        const float* __restrict__ cb, float* __restrict__ uc)
{
    int e = blockIdx.x * 256 + threadIdx.x;
    int m = blockIdx.y;
    int b = m >> 9, l = m & (LL - 1);
    float acc = cb[e];
    #pragma unroll
    for (int k = 0; k < KC; k++) {
        int ll = l + k - (KC - 1);
        float uv = (ll >= 0) ? ug[((size_t)(b * LL + ll)) * (2 * ED) + e] : 0.0f;
        acc = fmaf(uv, cw[e * KC + k], acc);
    }
    uc[(size_t)m * ED + e] = siluf(acc);
}

// ================= chunked selective scan ==================================
// pass1: grid (ED/256, NC, B), block 256 (one e per thread)
__global__ __launch_bounds__(256) void scan_pass1(
        const float* __restrict__ dtb, const float* __restrict__ ucb,
        const float* __restrict__ spb, const float* __restrict__ A_log,
        float* __restrict__ hfin, float* __restrict__ sumdt)
{
    int e = blockIdx.x * 256 + threadIdx.x;
    int c = blockIdx.y;
    int b = blockIdx.z;
    float a[NST], h[NST];
    const float4* ap = reinterpret_cast<const float4*>(A_log + (size_t)e * NST);
    #pragma unroll
    for (int q = 0; q < 4; q++) {
        float4 v = ap[q];
        a[4*q+0] = -expf(v.x); a[4*q+1] = -expf(v.y);
        a[4*q+2] = -expf(v.z); a[4*q+3] = -expf(v.w);
    }
    #pragma unroll
    for (int n = 0; n < NST; n++) h[n] = 0.0f;
    float sdt = 0.0f;
    int m0 = b * LL + c * CL;
    for (int l = 0; l < CL; l++) {
        int m = m0 + l;
        float dtv = dtb[(size_t)m * ED + e];
        float ucv = ucb[(size_t)m * ED + e];
        const float4* bp = reinterpret_cast<const float4*>(spb + (size_t)m * SP + DTR);
        float x = dtv * ucv;
        sdt += dtv;
        #pragma unroll
        for (int q = 0; q < 4; q++) {
            float4 bv = bp[q];
            h[4*q+0] = fmaf(expf(dtv * a[4*q+0]), h[4*q+0], x * bv.x);
            h[4*q+1] = fmaf(expf(dtv * a[4*q+1]), h[4*q+1], x * bv.y);
            h[4*q+2] = fmaf(expf(dtv * a[4*q+2]), h[4*q+2], x * bv.z);
            h[4*q+3] = fmaf(expf(dtv * a[4*q+3]), h[4*q+3], x * bv.w);
        }
    }
    float* hf = hfin + (((size_t)(b * ED + e)) * NC + c) * NST;
    #pragma unroll
    for (int n = 0; n < NST; n++) hf[n] = h[n];
    sumdt[((size_t)(b * ED + e)) * NC + c] = sdt;
}

// mid: thread per (b,e,n); grid B*ED*NST/256
__global__ __launch_bounds__(256) void scan_mid(
        const float* __restrict__ hfin, const float* __restrict__ sumdt,
        const float* __restrict__ A_log, float* __restrict__ hstart)
{
    int gid = blockIdx.x * 256 + threadIdx.x;   // (b*ED+e)*16 + n
    int n = gid & 15;
    int be = gid >> 4;
    int e = be % ED;
    float a = -expf(A_log[(size_t)e * NST + n]);
    float h = 0.0f;
    const float* hf = hfin + (size_t)be * NC * NST;
    const float* sd = sumdt + (size_t)be * NC;
    float* hs = hstart + (size_t)be * NC * NST;
    for (int c = 0; c < NC; c++) {
        hs[c * NST + n] = h;
        h = fmaf(expf(a * sd[c]), h, hf[c * NST + n]);
    }
}

// pass2: grid (ED/256, NC, B), block 256
__global__ __launch_bounds__(256) void scan_pass2(
        const float* __restrict__ dtb, const float* __restrict__ ucb,
        const float* __restrict__ spb, const float* __restrict__ ugb,
        const float* __restrict__ A_log, const float* __restrict__ Dp,
        const float* __restrict__ hstart, float* __restrict__ yb)
{
    int e = blockIdx.x * 256 + threadIdx.x;
    int c = blockIdx.y;
    int b = blockIdx.z;
    float a[NST], h[NST];
    const float4* ap = reinterpret_cast<const float4*>(A_log + (size_t)e * NST);
    #pragma unroll
    for (int q = 0; q < 4; q++) {
        float4 v = ap[q];
        a[4*q+0] = -expf(v.x); a[4*q+1] = -expf(v.y);
        a[4*q+2] = -expf(v.z); a[4*q+3] = -expf(v.w);
    }
    const float* hs = hstart + (((size_t)(b * ED + e)) * NC + c) * NST;
    #pragma unroll
    for (int n = 0; n < NST; n++) h[n] = hs[n];
    float dpv = Dp[e];
    int m0 = b * LL + c * CL;
    for (int l = 0; l < CL; l++) {
        int m = m0 + l;
        float dtv = dtb[(size_t)m * ED + e];
        float ucv = ucb[(size_t)m * ED + e];
        const float4* bp = reinterpret_cast<const float4*>(spb + (size_t)m * SP + DTR);
        const float4* cp = reinterpret_cast<const float4*>(spb + (size_t)m * SP + DTR + NST);
        float g = ugb[(size_t)m * (2 * ED) + ED + e];
        float x = dtv * ucv;
        float y0 = 0.0f, y1 = 0.0f, y2 = 0.0f, y3 = 0.0f;
        #pragma unroll
        for (int q = 0; q < 4; q++) {
            float4 bv = bp[q];
            float4 cv = cp[q];
            h[4*q+0] = fmaf(expf(dtv * a[4*q+0]), h[4*q+0], x * bv.x);
            h[4*q+1] = fmaf(expf(dtv * a[4*q+1]), h[4*q+1], x * bv.y);
            h[4*q+2] = fmaf(expf(dtv * a[4*q+2]), h[4*q+2], x * bv.z);
            h[4*q+3] = fmaf(expf(dtv * a[4*q+3]), h[4*q+3], x * bv.w);
            y0 = fmaf(h[4*q+0], cv.x, y0);
            y1 = fmaf(h[4*q+1], cv.y, y1);
            y2 = fmaf(h[4*q+2], cv.z, y2);
            y3 = fmaf(h[4*q+3], cv.w, y3);
        }
        float yv = (y0 + y1) + (y2 + y3) + ucv * dpv;
        yb[(size_t)m * ED + e] = yv * siluf(g);
    }
}

extern "C" void kernel_launch(void* const* d_in, const int* in_sizes, int n_in,
                              void* d_out, int out_size, void* d_ws, size_t ws_size,
                              hipStream_t stream) {
    const int*   src    = (const int*)  d_in[0];
    const float* emb    = (const float*)d_in[1];
    const float* norm_w = (const float*)d_in[2];
    const float* in_prj = (const float*)d_in[3];
    const float* conv_w = (const float*)d_in[4];
    const float* conv_b = (const float*)d_in[5];
    const float* x_prj  = (const float*)d_in[6];
    const float* dt_w   = (const float*)d_in[7];
    const float* dt_b   = (const float*)d_in[8];
    const float* A_log  = (const float*)d_in[9];
    const float* Dp     = (const float*)d_in[10];
    const float* out_p  = (const float*)d_in[11];
    const float* normf  = (const float*)d_in[12];
    float* out = (float*)d_out;

    float* ws    = (float*)d_ws;
    float* h     = ws;                              // M*D
    float* xn    = h     + (size_t)MM * DDIM;       // M*D
    float* ug    = xn    + (size_t)MM * DDIM;       // M*2ED
    float* ucb   = ug    + (size_t)MM * 2 * ED;     // M*ED
    float* spb   = ucb   + (size_t)MM * ED;         // M*SP
    float* dtbf  = spb   + (size_t)MM * SP;         // M*ED
    float* yb    = dtbf  + (size_t)MM * ED;         // M*ED
    float* hfin  = yb    + (size_t)MM * ED;         // B*ED*NC*NST
    float* sumdt = hfin  + (size_t)BB * ED * NC * NST; // B*ED*NC
    float* hstart= sumdt + (size_t)BB * ED * NC;    // B*ED*NC*NST

    embed_kernel<<<MM, 256, 0, stream>>>(src, emb, h);

    for (int layer = 0; layer < NL; layer++) {
        rmsnorm_kernel<<<MM, 256, 0, stream>>>(h, norm_w + (size_t)layer * DDIM, xn);
        // ug = xn @ in_proj^T   [M, 2ED]   (bf16 MFMA)
        gemm_bf16nt<<<dim3(MM / 128, 2 * ED / 128), 256, 0, stream>>>(
            xn, DDIM, in_prj + (size_t)layer * 2 * ED * DDIM, DDIM,
            ug, 2 * ED, DDIM, 0);
        conv_silu_kernel<<<dim3(ED / 256, MM), 256, 0, stream>>>(
            ug, conv_w + (size_t)layer * ED * KC, conv_b + (size_t)layer * ED, ucb);
        // sp = uc @ x_proj^T    [M, 80]    (fp32)
        sgemm_nt<<<dim3(MM / 64, 2), 256, 0, stream>>>(
            ucb, ED, x_prj + (size_t)layer * SP * ED, ED,
            spb, SP, SP, ED, 0, nullptr);
        // dt = softplus(sp[:, :48] @ dt_w^T + dt_b)   [M, ED]   (fp32)
        sgemm_nt<<<dim3(MM / 64, ED / 64), 256, 0, stream>>>(
            spb, SP, dt_w + (size_t)layer * ED * DTR, DTR,
            dtbf, ED, ED, DTR, 1, dt_b + (size_t)layer * ED);
        // chunked scan
        scan_pass1<<<dim3(ED / 256, NC, BB), 256, 0, stream>>>(
            dtbf, ucb, spb, A_log + (size_t)layer * ED * NST, hfin, sumdt);
        scan_mid<<<BB * ED * NST / 256, 256, 0, stream>>>(
            hfin, sumdt, A_log + (size_t)layer * ED * NST, hstart);
        scan_pass2<<<dim3(ED / 256, NC, BB), 256, 0, stream>>>(
            dtbf, ucb, spb, ug, A_log + (size_t)layer * ED * NST,
            Dp + (size_t)layer * ED, hstart, yb);
        // h += y @ out_proj^T   [M, D]     (bf16 MFMA, += epilogue)
        gemm_bf16nt<<<dim3(MM / 128, DDIM / 128), 256, 0, stream>>>(
            yb, ED, out_p + (size_t)layer * DDIM * ED, ED,
            h, DDIM, ED, 2);
    }

    rmsnorm_kernel<<<MM, 256, 0, stream>>>(h, normf, xn);
    // logits = xn @ embed^T, stored transposed to [L, B, V]   (bf16 MFMA)
    gemm_bf16nt<<<dim3(MM / 128, VV / 128), 256, 0, stream>>>(
        xn, DDIM, emb, DDIM, out, VV, DDIM, 3);
}

// Round 4
// 5728.771 us; speedup vs baseline: 4.0537x; 1.7059x over previous
//
#include <hip/hip_runtime.h>
#include <hip/hip_bf16.h>
#include <math.h>

// Problem dims (fixed by reference)
#define NL   24
#define DDIM 768
#define ED   1536
#define NST  16
#define KC   4
#define DTR  48
#define VV   1024
#define LL   512
#define BB   2
#define MM   (BB*LL)      // 1024
#define SP   80           // DT_RANK + 2N

// scan chunking
#define NC   32           // chunks per sequence
#define CL   (LL/NC)      // 16 timesteps per chunk

// x_proj split-K
#define XKS  16           // K splits
#define XKC  (ED/XKS)     // 96 per split

typedef __bf16 bf16x8 __attribute__((ext_vector_type(8)));
typedef float  floatx4 __attribute__((ext_vector_type(4)));
typedef unsigned short ushort8 __attribute__((ext_vector_type(8)));

__device__ __forceinline__ float softplusf(float x) {
    return fmaxf(x, 0.0f) + log1pf(expf(-fabsf(x)));
}
__device__ __forceinline__ float siluf(float x) {
    return x / (1.0f + expf(-x));
}
__device__ __forceinline__ unsigned short f2bf(float x) {
    unsigned int u = __builtin_bit_cast(unsigned int, x);
    u += 0x7FFFu + ((u >> 16) & 1u);   // round-to-nearest-even
    return (unsigned short)(u >> 16);
}

// ---------------- embedding: h[m,:] = embed[src[l,b],:], m = b*L + l -------
__global__ __launch_bounds__(256) void embed_kernel(
        const int* __restrict__ src, const float* __restrict__ emb,
        float* __restrict__ h)
{
    int m = blockIdx.x;
    int b = m >> 9;           // m / L
    int l = m & (LL - 1);
    int v = src[l * BB + b];
    const float* er = emb + (size_t)v * DDIM;
    float* hr = h + (size_t)m * DDIM;
    for (int d = threadIdx.x; d < DDIM; d += 256) hr[d] = er[d];
}

// ---------------- rmsnorm: o[m,:] = x[m,:] * rsqrt(mean(x^2)+eps) * w ------
__global__ __launch_bounds__(256) void rmsnorm_kernel(
        const float* __restrict__ x, const float* __restrict__ w,
        float* __restrict__ o)
{
    __shared__ float red[4];
    int m = blockIdx.x, tid = threadIdx.x;
    const float* xr = x + (size_t)m * DDIM;
    float v0 = xr[tid], v1 = xr[tid + 256], v2 = xr[tid + 512];
    float s = v0 * v0 + v1 * v1 + v2 * v2;
    #pragma unroll
    for (int off = 32; off; off >>= 1) s += __shfl_down(s, off);
    if ((tid & 63) == 0) red[tid >> 6] = s;
    __syncthreads();
    float tot = red[0] + red[1] + red[2] + red[3];
    float scale = rsqrtf(tot * (1.0f / DDIM) + 1e-5f);
    float* orow = o + (size_t)m * DDIM;
    orow[tid]       = v0 * scale * w[tid];
    orow[tid + 256] = v1 * scale * w[tid + 256];
    orow[tid + 512] = v2 * scale * w[tid + 512];
}

// ============ bf16 MFMA GEMM: C[m,n] = sum_k A[m,k]*W[n,k] =================
// A fp32 [M,lda] row-major, W fp32 [N,ldb] row-major (both K-contiguous).
// fp32 tiles are converted to bf16 while staging into LDS.
// BM=BN=128, BK=32; 256 threads = 4 waves in 2x2; wave does 4x4 16x16 MFMAs.
// modes: 0 = store; 2 = C += acc; 3 = logits store with [B,L]->[L,B] transpose
__global__ __launch_bounds__(256) void gemm_bf16nt(
        const float* __restrict__ A, int lda,
        const float* __restrict__ W, int ldb,
        float* __restrict__ C, int ldc,
        int Kdim, int mode)
{
    __shared__ unsigned short As[128 * 32];
    __shared__ unsigned short Bs[128 * 32];
    int tid  = threadIdx.x;
    int lane = tid & 63;
    int wave = tid >> 6;
    int wm = wave >> 1, wn = wave & 1;
    int rowBase = blockIdx.x * 128;
    int colBase = blockIdx.y * 128;

    floatx4 acc[4][4];
    #pragma unroll
    for (int i = 0; i < 4; i++)
        #pragma unroll
        for (int j = 0; j < 4; j++)
            acc[i][j] = (floatx4){0.f, 0.f, 0.f, 0.f};

    int kc  = lane >> 4;      // k-chunk 0..3 for fragment reads
    int lm  = lane & 15;

    for (int kk = 0; kk < Kdim; kk += 32) {
        // ---- stage 128x32 fp32 -> bf16 LDS, for A and W ----
        #pragma unroll
        for (int hh = 0; hh < 2; hh++) {
            int q  = tid + hh * 256;          // chunk id 0..511
            int r  = q >> 2;                  // tile row 0..127
            int cg = q & 3;                   // global col-chunk
            int cs = cg ^ ((r >> 1) & 3);     // swizzled LDS slot
            const float4* pa = reinterpret_cast<const float4*>(
                A + (size_t)(rowBase + r) * lda + kk + cg * 8);
            float4 a0 = pa[0], a1 = pa[1];
            const float4* pb = reinterpret_cast<const float4*>(
                W + (size_t)(colBase + r) * ldb + kk + cg * 8);
            float4 b0 = pb[0], b1 = pb[1];
            ushort8 va = {f2bf(a0.x), f2bf(a0.y), f2bf(a0.z), f2bf(a0.w),
                          f2bf(a1.x), f2bf(a1.y), f2bf(a1.z), f2bf(a1.w)};
            ushort8 vb = {f2bf(b0.x), f2bf(b0.y), f2bf(b0.z), f2bf(b0.w),
                          f2bf(b1.x), f2bf(b1.y), f2bf(b1.z), f2bf(b1.w)};
            *reinterpret_cast<ushort8*>(&As[(r * 4 + cs) * 8]) = va;
            *reinterpret_cast<ushort8*>(&Bs[(r * 4 + cs) * 8]) = vb;
        }
        __syncthreads();

        // ---- fragments: A[m = lane&15][k = (lane>>4)*8 + j] ----
        bf16x8 af[4], bff[4];
        #pragma unroll
        for (int i = 0; i < 4; i++) {
            int m = wm * 64 + i * 16 + lm;
            af[i]  = *reinterpret_cast<bf16x8*>(&As[(m * 4 + (kc ^ ((m >> 1) & 3))) * 8]);
            int n = wn * 64 + i * 16 + lm;
            bff[i] = *reinterpret_cast<bf16x8*>(&Bs[(n * 4 + (kc ^ ((n >> 1) & 3))) * 8]);
        }
        #pragma unroll
        for (int i = 0; i < 4; i++)
            #pragma unroll
            for (int j = 0; j < 4; j++)
                acc[i][j] = __builtin_amdgcn_mfma_f32_16x16x32_bf16(
                    af[i], bff[j], acc[i][j], 0, 0, 0);
        __syncthreads();
    }

    // ---- epilogue: D col = lane&15, row = (lane>>4)*4 + reg ----
    int c4 = (lane >> 4) * 4;
    #pragma unroll
    for (int i = 0; i < 4; i++) {
        #pragma unroll
        for (int j = 0; j < 4; j++) {
            floatx4 v = acc[i][j];
            int col = colBase + wn * 64 + j * 16 + lm;
            #pragma unroll
            for (int p = 0; p < 4; p++) {
                int row = rowBase + wm * 64 + i * 16 + c4 + p;
                if (mode == 0) {
                    C[(size_t)row * ldc + col] = v[p];
                } else if (mode == 2) {
                    C[(size_t)row * ldc + col] += v[p];
                } else {
                    int l = row & (LL - 1), b = row >> 9;
                    C[((size_t)l * BB + b) * ldc + col] = v[p];
                }
            }
        }
    }
}

// ---------------- generic fp32 SGEMM (dt GEMM) -----------------------------
// modes: 0 = store; 1 = softplus(acc + bias[n])
__global__ __launch_bounds__(256) void sgemm_nt(
        const float* __restrict__ A, int lda,
        const float* __restrict__ W, int ldb,
        float* __restrict__ C, int ldc,
        int Nmat, int Kdim, int mode, const float* __restrict__ bias)
{
    __shared__ float As[16][65];
    __shared__ float Ws[16][65];
    int tid = threadIdx.x;
    int tx = tid & 15, ty = tid >> 4;
    int rowBase = blockIdx.x * 64;
    int colBase = blockIdx.y * 64;
    float acc[4][4] = {};

    for (int kk = 0; kk < Kdim; kk += 16) {
        #pragma unroll
        for (int i = 0; i < 4; i++) {
            int idx = tid + i * 256;
            int r = idx >> 4, kc = idx & 15;
            As[kc][r] = A[(size_t)(rowBase + r) * lda + kk + kc];
            int cG = colBase + r;
            Ws[kc][r] = (cG < Nmat) ? W[(size_t)cG * ldb + kk + kc] : 0.0f;
        }
        __syncthreads();
        #pragma unroll
        for (int k = 0; k < 16; k++) {
            float av[4], bv[4];
            #pragma unroll
            for (int i = 0; i < 4; i++) av[i] = As[k][ty + 16 * i];
            #pragma unroll
            for (int j = 0; j < 4; j++) bv[j] = Ws[k][tx + 16 * j];
            #pragma unroll
            for (int i = 0; i < 4; i++)
                #pragma unroll
                for (int j = 0; j < 4; j++)
                    acc[i][j] = fmaf(av[i], bv[j], acc[i][j]);
        }
        __syncthreads();
    }

    #pragma unroll
    for (int i = 0; i < 4; i++) {
        int m = rowBase + ty + 16 * i;
        #pragma unroll
        for (int j = 0; j < 4; j++) {
            int n = colBase + tx + 16 * j;
            if (n >= Nmat) continue;
            float v = acc[i][j];
            if (mode == 0) {
                C[(size_t)m * ldc + n] = v;
            } else {
                C[(size_t)m * ldc + n] = softplusf(v + bias[n]);
            }
        }
    }
}

// ---------------- x_proj split-K: part[ks][m][0:80] ------------------------
// grid (MM/64, XKS), block 256. Each block: 64 rows x 80 cols x 96 K.
__global__ __launch_bounds__(256) void xproj_partial(
        const float* __restrict__ ucb, const float* __restrict__ W,
        float* __restrict__ part)
{
    __shared__ float As[16][65];
    __shared__ float Ws[16][88];
    int tid = threadIdx.x;
    int tx = tid & 15;        // col base (5 cols spaced 16)
    int ty = tid >> 4;        // row base (4 rows spaced 16)
    int rowBase = blockIdx.x * 64;
    int k0 = blockIdx.y * XKC;
    float acc[4][5] = {};

    for (int kk = 0; kk < XKC; kk += 16) {
        #pragma unroll
        for (int i = 0; i < 4; i++) {
            int idx = tid + i * 256;
            int r = idx >> 4, kc = idx & 15;
            As[kc][r] = ucb[(size_t)(rowBase + r) * ED + k0 + kk + kc];
        }
        #pragma unroll
        for (int i = 0; i < 5; i++) {
            int idx = tid + i * 256;        // 0..1279
            int c = idx >> 4, kc = idx & 15;
            Ws[kc][c] = W[(size_t)c * ED + k0 + kk + kc];
        }
        __syncthreads();
        #pragma unroll
        for (int k = 0; k < 16; k++) {
            float av[4], bv[5];
            #pragma unroll
            for (int i = 0; i < 4; i++) av[i] = As[k][ty + 16 * i];
            #pragma unroll
            for (int j = 0; j < 5; j++) bv[j] = Ws[k][tx + 16 * j];
            #pragma unroll
            for (int i = 0; i < 4; i++)
                #pragma unroll
                for (int j = 0; j < 5; j++)
                    acc[i][j] = fmaf(av[i], bv[j], acc[i][j]);
        }
        __syncthreads();
    }

    float* p = part + ((size_t)blockIdx.y * MM + rowBase) * SP;
    #pragma unroll
    for (int i = 0; i < 4; i++)
        #pragma unroll
        for (int j = 0; j < 5; j++)
            p[(ty + 16 * i) * SP + tx + 16 * j] = acc[i][j];
}

// reduce 16 partial slices -> spb[m][0:80]
__global__ __launch_bounds__(256) void xproj_reduce(
        const float* __restrict__ part, float* __restrict__ spb)
{
    int idx = blockIdx.x * 256 + threadIdx.x;   // over MM*SP = 81920
    float s = 0.0f;
    #pragma unroll
    for (int ks = 0; ks < XKS; ks++)
        s += part[(size_t)ks * MM * SP + idx];
    spb[idx] = s;
}

// ---------------- depthwise causal conv (K=4) + bias + SiLU ----------------
__global__ __launch_bounds__(256) void conv_silu_kernel(
        const float* __restrict__ ug, const float* __restrict__ cw,
        const float* __restrict__ cb, float* __restrict__ uc)
{
    int e = blockIdx.x * 256 + threadIdx.x;
    int m = blockIdx.y;
    int b = m >> 9, l = m & (LL - 1);
    float acc = cb[e];
    #pragma unroll
    for (int k = 0; k < KC; k++) {
        int ll = l + k - (KC - 1);
        float uv = (ll >= 0) ? ug[((size_t)(b * LL + ll)) * (2 * ED) + e] : 0.0f;
        acc = fmaf(uv, cw[e * KC + k], acc);
    }
    uc[(size_t)m * ED + e] = siluf(acc);
}

// ================= chunked selective scan ==================================
// pass1: grid (ED/256, NC, B), block 256 (one e per thread)
__global__ __launch_bounds__(256) void scan_pass1(
        const float* __restrict__ dtb, const float* __restrict__ ucb,
        const float* __restrict__ spb, const float* __restrict__ A_log,
        float* __restrict__ hfin, float* __restrict__ sumdt)
{
    int e = blockIdx.x * 256 + threadIdx.x;
    int c = blockIdx.y;
    int b = blockIdx.z;
    float a[NST], h[NST];
    const float4* ap = reinterpret_cast<const float4*>(A_log + (size_t)e * NST);
    #pragma unroll
    for (int q = 0; q < 4; q++) {
        float4 v = ap[q];
        a[4*q+0] = -expf(v.x); a[4*q+1] = -expf(v.y);
        a[4*q+2] = -expf(v.z); a[4*q+3] = -expf(v.w);
    }
    #pragma unroll
    for (int n = 0; n < NST; n++) h[n] = 0.0f;
    float sdt = 0.0f;
    int m0 = b * LL + c * CL;
    for (int l = 0; l < CL; l++) {
        int m = m0 + l;
        float dtv = dtb[(size_t)m * ED + e];
        float ucv = ucb[(size_t)m * ED + e];
        const float4* bp = reinterpret_cast<const float4*>(spb + (size_t)m * SP + DTR);
        float x = dtv * ucv;
        sdt += dtv;
        #pragma unroll
        for (int q = 0; q < 4; q++) {
            float4 bv = bp[q];
            h[4*q+0] = fmaf(expf(dtv * a[4*q+0]), h[4*q+0], x * bv.x);
            h[4*q+1] = fmaf(expf(dtv * a[4*q+1]), h[4*q+1], x * bv.y);
            h[4*q+2] = fmaf(expf(dtv * a[4*q+2]), h[4*q+2], x * bv.z);
            h[4*q+3] = fmaf(expf(dtv * a[4*q+3]), h[4*q+3], x * bv.w);
        }
    }
    float* hf = hfin + (((size_t)(b * ED + e)) * NC + c) * NST;
    #pragma unroll
    for (int n = 0; n < NST; n++) hf[n] = h[n];
    sumdt[((size_t)(b * ED + e)) * NC + c] = sdt;
}

// mid: thread per (b,e,n); grid B*ED*NST/256
__global__ __launch_bounds__(256) void scan_mid(
        const float* __restrict__ hfin, const float* __restrict__ sumdt,
        const float* __restrict__ A_log, float* __restrict__ hstart)
{
    int gid = blockIdx.x * 256 + threadIdx.x;   // (b*ED+e)*16 + n
    int n = gid & 15;
    int be = gid >> 4;
    int e = be % ED;
    float a = -expf(A_log[(size_t)e * NST + n]);
    float h = 0.0f;
    const float* hf = hfin + (size_t)be * NC * NST;
    const float* sd = sumdt + (size_t)be * NC;
    float* hs = hstart + (size_t)be * NC * NST;
    for (int c = 0; c < NC; c++) {
        hs[c * NST + n] = h;
        h = fmaf(expf(a * sd[c]), h, hf[c * NST + n]);
    }
}

// pass2: grid (ED/256, NC, B), block 256
__global__ __launch_bounds__(256) void scan_pass2(
        const float* __restrict__ dtb, const float* __restrict__ ucb,
        const float* __restrict__ spb, const float* __restrict__ ugb,
        const float* __restrict__ A_log, const float* __restrict__ Dp,
        const float* __restrict__ hstart, float* __restrict__ yb)
{
    int e = blockIdx.x * 256 + threadIdx.x;
    int c = blockIdx.y;
    int b = blockIdx.z;
    float a[NST], h[NST];
    const float4* ap = reinterpret_cast<const float4*>(A_log + (size_t)e * NST);
    #pragma unroll
    for (int q = 0; q < 4; q++) {
        float4 v = ap[q];
        a[4*q+0] = -expf(v.x); a[4*q+1] = -expf(v.y);
        a[4*q+2] = -expf(v.z); a[4*q+3] = -expf(v.w);
    }
    const float* hs = hstart + (((size_t)(b * ED + e)) * NC + c) * NST;
    #pragma unroll
    for (int n = 0; n < NST; n++) h[n] = hs[n];
    float dpv = Dp[e];
    int m0 = b * LL + c * CL;
    for (int l = 0; l < CL; l++) {
        int m = m0 + l;
        float dtv = dtb[(size_t)m * ED + e];
        float ucv = ucb[(size_t)m * ED + e];
        const float4* bp = reinterpret_cast<const float4*>(spb + (size_t)m * SP + DTR);
        const float4* cp = reinterpret_cast<const float4*>(spb + (size_t)m * SP + DTR + NST);
        float g = ugb[(size_t)m * (2 * ED) + ED + e];
        float x = dtv * ucv;
        float y0 = 0.0f, y1 = 0.0f, y2 = 0.0f, y3 = 0.0f;
        #pragma unroll
        for (int q = 0; q < 4; q++) {
            float4 bv = bp[q];
            float4 cv = cp[q];
            h[4*q+0] = fmaf(expf(dtv * a[4*q+0]), h[4*q+0], x * bv.x);
            h[4*q+1] = fmaf(expf(dtv * a[4*q+1]), h[4*q+1], x * bv.y);
            h[4*q+2] = fmaf(expf(dtv * a[4*q+2]), h[4*q+2], x * bv.z);
            h[4*q+3] = fmaf(expf(dtv * a[4*q+3]), h[4*q+3], x * bv.w);
            y0 = fmaf(h[4*q+0], cv.x, y0);
            y1 = fmaf(h[4*q+1], cv.y, y1);
            y2 = fmaf(h[4*q+2], cv.z, y2);
            y3 = fmaf(h[4*q+3], cv.w, y3);
        }
        float yv = (y0 + y1) + (y2 + y3) + ucv * dpv;
        yb[(size_t)m * ED + e] = yv * siluf(g);
    }
}

extern "C" void kernel_launch(void* const* d_in, const int* in_sizes, int n_in,
                              void* d_out, int out_size, void* d_ws, size_t ws_size,
                              hipStream_t stream) {
    const int*   src    = (const int*)  d_in[0];
    const float* emb    = (const float*)d_in[1];
    const float* norm_w = (const float*)d_in[2];
    const float* in_prj = (const float*)d_in[3];
    const float* conv_w = (const float*)d_in[4];
    const float* conv_b = (const float*)d_in[5];
    const float* x_prj  = (const float*)d_in[6];
    const float* dt_w   = (const float*)d_in[7];
    const float* dt_b   = (const float*)d_in[8];
    const float* A_log  = (const float*)d_in[9];
    const float* Dp     = (const float*)d_in[10];
    const float* out_p  = (const float*)d_in[11];
    const float* normf  = (const float*)d_in[12];
    float* out = (float*)d_out;

    float* ws    = (float*)d_ws;
    float* h     = ws;                              // M*D
    float* xn    = h     + (size_t)MM * DDIM;       // M*D
    float* ug    = xn    + (size_t)MM * DDIM;       // M*2ED
    float* ucb   = ug    + (size_t)MM * 2 * ED;     // M*ED
    float* spb   = ucb   + (size_t)MM * ED;         // M*SP
    float* dtbf  = spb   + (size_t)MM * SP;         // M*ED
    float* yb    = dtbf  + (size_t)MM * ED;         // M*ED
    float* hfin  = yb    + (size_t)MM * ED;         // B*ED*NC*NST (also x_proj partials: XKS*MM*SP <= this)
    float* sumdt = hfin  + (size_t)BB * ED * NC * NST; // B*ED*NC
    float* hstart= sumdt + (size_t)BB * ED * NC;    // B*ED*NC*NST
    float* xpart = hfin;                            // reuse: dead before scan_pass1 writes hfin

    embed_kernel<<<MM, 256, 0, stream>>>(src, emb, h);

    for (int layer = 0; layer < NL; layer++) {
        rmsnorm_kernel<<<MM, 256, 0, stream>>>(h, norm_w + (size_t)layer * DDIM, xn);
        // ug = xn @ in_proj^T   [M, 2ED]   (bf16 MFMA)
        gemm_bf16nt<<<dim3(MM / 128, 2 * ED / 128), 256, 0, stream>>>(
            xn, DDIM, in_prj + (size_t)layer * 2 * ED * DDIM, DDIM,
            ug, 2 * ED, DDIM, 0);
        conv_silu_kernel<<<dim3(ED / 256, MM), 256, 0, stream>>>(
            ug, conv_w + (size_t)layer * ED * KC, conv_b + (size_t)layer * ED, ucb);
        // sp = uc @ x_proj^T    [M, 80]    (fp32 split-K + reduce)
        xproj_partial<<<dim3(MM / 64, XKS), 256, 0, stream>>>(
            ucb, x_prj + (size_t)layer * SP * ED, xpart);
        xproj_reduce<<<MM * SP / 256, 256, 0, stream>>>(xpart, spb);
        // dt = softplus(sp[:, :48] @ dt_w^T + dt_b)   [M, ED]   (fp32)
        sgemm_nt<<<dim3(MM / 64, ED / 64), 256, 0, stream>>>(
            spb, SP, dt_w + (size_t)layer * ED * DTR, DTR,
            dtbf, ED, ED, DTR, 1, dt_b + (size_t)layer * ED);
        // chunked scan
        scan_pass1<<<dim3(ED / 256, NC, BB), 256, 0, stream>>>(
            dtbf, ucb, spb, A_log + (size_t)layer * ED * NST, hfin, sumdt);
        scan_mid<<<BB * ED * NST / 256, 256, 0, stream>>>(
            hfin, sumdt, A_log + (size_t)layer * ED * NST, hstart);
        scan_pass2<<<dim3(ED / 256, NC, BB), 256, 0, stream>>>(
            dtbf, ucb, spb, ug, A_log + (size_t)layer * ED * NST,
            Dp + (size_t)layer * ED, hstart, yb);
        // h += y @ out_proj^T   [M, D]     (bf16 MFMA, += epilogue)
        gemm_bf16nt<<<dim3(MM / 128, DDIM / 128), 256, 0, stream>>>(
            yb, ED, out_p + (size_t)layer * DDIM * ED, ED,
            h, DDIM, ED, 2);
    }

    rmsnorm_kernel<<<MM, 256, 0, stream>>>(h, normf, xn);
    // logits = xn @ embed^T, stored transposed to [L, B, V]   (bf16 MFMA)
    gemm_bf16nt<<<dim3(MM / 128, VV / 128), 256, 0, stream>>>(
        xn, DDIM, emb, DDIM, out, VV, DDIM, 3);
}